// Round 10
// baseline (78.946 us; speedup 1.0000x reference)
//
#include <hip/hip_runtime.h>
#include <math.h>

// MaxYager2d: out[b,f,si,sj] = max(0, 1 - (min_{c,kh,kw} A[b,c,si+kh,sj+kw] + BW[c,kh,kw,f])^(2/3))
// where A = (1-x)^1.5, BW = (1-w)^1.5.  Max over J commutes with the
// monotone-decreasing Yager combine -> tropical min-plus 3x3 conv.
//
// r10: phase diversity. Each (b,row) split into 2 blocks of 512 thr by
// f-half: grid 512 = 2 blocks/CU (16 waves/CU total) so one block's
// global-load staging hides under the other's compute; 8-wave barriers.
// B staged coalesced per block (16 f columns, 64B segments); A staged as r9
// ([cp][kr][68] half2, fused (1-x)^1.5, dup x2 per row - cheap). Compute
// loop identical to r9 (broadcast b128 B, no SMEM) + split min-chains.

#define CIN  32
#define CP   16   // channel pairs
#define FOUT 32
#define KS   3
#define HW   66   // input spatial
#define SS   64   // output spatial
#define NB   4    // batch
#define FH   16   // f per block

typedef _Float16 half2_t __attribute__((ext_vector_type(2)));
typedef _Float16 half8_t __attribute__((ext_vector_type(8)));   // 4 half2 = 16B

static __device__ __forceinline__ half2_t mk2(float a, float b) {
    half2_t r; r.x = (_Float16)a; r.y = (_Float16)b; return r;
}

union bvec {
    half8_t v8;
    half2_t v2[4];
};

__global__ __launch_bounds__(512, 4) void yager_one(
    const float* __restrict__ x, const float* __restrict__ w,
    float* __restrict__ out)
{
    __shared__ half2_t ldsA[CP][KS][68];       // 13.1 KB  [cp][kr][col]
    __shared__ _Float16 ldsB[FH][9][CIN];      // 9.2 KB   [fi][t][c]

    const int tid   = threadIdx.x;
    const int fhalf = blockIdx.x & 1;
    const int rowb  = blockIdx.x >> 1;
    const int row   = rowb & (SS - 1);
    const int b     = rowb >> 6;

    // --- stage B (this block's 16 f): 4608 elems = exactly 9/thread.
    // i -> [j][fi]; global read w[j*32 + fhalf*16 + fi]: 64B segments, coalesced.
#pragma unroll
    for (int k = 0; k < 9; ++k) {
        int i  = tid + k * 512;
        int fi = i & (FH - 1);
        int j  = i >> 4;                  // 0..287
        float v = w[j * FOUT + fhalf * FH + fi];
        int c  = j / 9;
        int t  = j - 9 * c;
        float tt = 1.0f - v;
        ldsB[fi][t][c] = (_Float16)(tt * sqrtf(tt));   // (1-w)^1.5
    }

    // --- stage A window (3 rows x 32 ch as 16 half2), fusing A = t*sqrt(t).
    for (int i = tid; i < CP * KS * HW; i += 512) {
        int cp  = i / (KS * HW);
        int r   = i - cp * (KS * HW);
        int kr  = r / HW;
        int col = r - kr * HW;
        const float* xp = x + ((size_t)(b * CIN + 2 * cp) * HW + row + kr) * HW + col;
        float t0 = 1.0f - xp[0];
        float t1 = 1.0f - xp[HW * HW];
        ldsA[cp][kr][col] = mk2(t0 * sqrtf(t0), t1 * sqrtf(t1));
    }
    __syncthreads();

    const int lane = tid & 63;                                     // output col
    const int wv   = __builtin_amdgcn_readfirstlane(tid >> 6);     // 0..7
    const int f0   = wv * 2;                                       // ldsB row
    const int fg   = fhalf * FH + f0;                              // global f

    // split min-chains (a/b) per f for ILP; min is exact, order-free.
    half2_t M0a = mk2(4.0f, 4.0f), M0b = M0a, M1a = M0a, M1b = M0a;

#pragma unroll
    for (int q = 0; q < 4; ++q) {       // cp groups of 4
        bvec bq0[9], bq1[9];
#pragma unroll
        for (int t = 0; t < 9; ++t) {   // wave-uniform broadcast b128
            bq0[t].v8 = *(const half8_t*)&ldsB[f0][t][8 * q];
            bq1[t].v8 = *(const half8_t*)&ldsB[f0 + 1][t][8 * q];
        }
#pragma unroll
        for (int i = 0; i < 4; ++i) {
            const int cp = 4 * q + i;
            half2_t a[KS][KS];
#pragma unroll
            for (int kr = 0; kr < KS; ++kr)
#pragma unroll
                for (int kw = 0; kw < KS; ++kw)
                    a[kr][kw] = ldsA[cp][kr][lane + kw];
#pragma unroll
            for (int t = 0; t < 9; ++t) {
                half2_t av = a[t / 3][t % 3];
                half2_t s0 = av + bq0[t].v2[i];
                half2_t s1 = av + bq1[t].v2[i];
                if (i & 1) { M0b = __builtin_elementwise_min(M0b, s0);
                             M1b = __builtin_elementwise_min(M1b, s1); }
                else       { M0a = __builtin_elementwise_min(M0a, s0);
                             M1a = __builtin_elementwise_min(M1a, s1); }
            }
        }
    }

    half2_t M0 = __builtin_elementwise_min(M0a, M0b);
    half2_t M1 = __builtin_elementwise_min(M1a, M1b);
    float m0 = fminf((float)M0.x, (float)M0.y);
    float m1 = fminf((float)M1.x, (float)M1.y);
    float r0 = 1.0f - exp2f(0.6666666667f * log2f(m0));
    float r1 = 1.0f - exp2f(0.6666666667f * log2f(m1));
    float* op = out + (((size_t)b * FOUT + fg) * SS + row) * SS + lane;
    op[0]       = fmaxf(r0, 0.0f);
    op[SS * SS] = fmaxf(r1, 0.0f);
}

extern "C" void kernel_launch(void* const* d_in, const int* in_sizes, int n_in,
                              void* d_out, int out_size, void* d_ws, size_t ws_size,
                              hipStream_t stream)
{
    const float* x = (const float*)d_in[0];   // [4,32,66,66] f32
    const float* w = (const float*)d_in[1];   // [288,32] f32
    float* out = (float*)d_out;               // [4,32,64,64] f32
    (void)d_ws; (void)ws_size;

    yager_one<<<NB * SS * 2, 512, 0, stream>>>(x, w, out);
}

// Round 11
// 42.840 us; speedup vs baseline: 1.8428x; 1.8428x over previous
//
#include <hip/hip_runtime.h>
#include <math.h>

// MaxYager2d: out[b,f,si,sj] = max(0, 1 - (min_{c,kh,kw} A[b,c,si+kh,sj+kw] + BW[c,kh,kw,f])^(2/3))
// where A = (1-x)^1.5, BW = (1-w)^1.5.  Max over J commutes with the
// monotone-decreasing Yager combine -> tropical min-plus 3x3 conv.
//
// r11: r9 structure, de-spilled + conflict-free + packed A.
//  - grid 512: each (b,row) split into 2 blocks of 512 thr by f-half
//    (2 blocks/CU -> staging of one overlaps compute of the other).
//    __launch_bounds__(512) ONLY (r10's ",4" caused a 64-VGPR cap ->
//    per-iteration scratch spill: 91 MB fetch / 170 MB write).
//  - ldsB padded to 40 halfs/row: b16 scatter-writes land 2-way (free)
//    instead of 8-way (r9/r10: 1.13M conflict cycles). b128 alignment kept.
//  - ldsA packs 4 channels per slot (half4, b64 loads): 72 b64/wave vs 96.
// Arithmetic identical to r9 -> absmax 0.00390625 unchanged.

#define CIN  32
#define FOUT 32
#define KS   3
#define HW   66   // input spatial
#define SS   64   // output spatial
#define NB   4    // batch
#define FH   16   // f per block
#define BPAD 40   // padded B row (CIN + 8)

typedef _Float16 half2_t __attribute__((ext_vector_type(2)));
typedef _Float16 half4_t __attribute__((ext_vector_type(4)));   // 8 B, b64
typedef _Float16 half8_t __attribute__((ext_vector_type(8)));   // 16 B, b128

static __device__ __forceinline__ half2_t mk2(float a, float b) {
    half2_t r; r.x = (_Float16)a; r.y = (_Float16)b; return r;
}

union bvec {
    half8_t v8;
    half2_t v2[4];
};

__global__ __launch_bounds__(512) void yager_one(
    const float* __restrict__ x, const float* __restrict__ w,
    float* __restrict__ out)
{
    __shared__ __align__(16) half4_t  ldsA[8][KS][68];     // 13.1 KB  [slot][kr][col], 4 ch/slot
    __shared__ __align__(16) _Float16 ldsB[FH][9][BPAD];   // 11.5 KB  [fi][t][ch], padded

    const int tid   = threadIdx.x;
    const int fhalf = blockIdx.x & 1;
    const int rowb  = blockIdx.x >> 1;
    const int row   = rowb & (SS - 1);
    const int b     = rowb >> 6;

    // --- stage B (this block's 16 f): 4608 elems, coalesced w reads.
    // i -> fi = i&15, j = i>>4 (0..287): c = j/9, t = j%9.
    // write stride over fi = 720 B -> bank stride 20 -> 2-way (free).
#pragma unroll
    for (int k = 0; k < 9; ++k) {
        int i  = tid + k * 512;
        int fi = i & (FH - 1);
        int j  = i >> 4;
        float v = w[j * FOUT + fhalf * FH + fi];
        int c  = j / 9;
        int t  = j - 9 * c;
        float tt = 1.0f - v;
        ldsB[fi][t][c] = (_Float16)(tt * sqrtf(tt));   // (1-w)^1.5
    }

    // --- stage A: slot s holds channels 4s..4s+3 as half4; A = t*sqrt(t).
    for (int i = tid; i < 8 * KS * HW; i += 512) {
        int s   = i / (KS * HW);
        int r   = i - s * (KS * HW);
        int kr  = r / HW;
        int col = r - kr * HW;
        const float* xp = x + ((size_t)(b * CIN + 4 * s) * HW + row + kr) * HW + col;
        float t0 = 1.0f - xp[0];
        float t1 = 1.0f - xp[HW * HW];
        float t2 = 1.0f - xp[2 * HW * HW];
        float t3 = 1.0f - xp[3 * HW * HW];
        half4_t v;
        v.x = (_Float16)(t0 * sqrtf(t0));
        v.y = (_Float16)(t1 * sqrtf(t1));
        v.z = (_Float16)(t2 * sqrtf(t2));
        v.w = (_Float16)(t3 * sqrtf(t3));
        ldsA[s][kr][col] = v;
    }
    __syncthreads();

    const int lane = tid & 63;                                  // output col
    const int wv   = __builtin_amdgcn_readfirstlane(tid >> 6);  // 0..7
    const int f0   = wv * 2;                                    // local f pair
    const int fg   = fhalf * FH + f0;                           // global f

    // two accumulators per f (h=0 / h=1) to shorten min dep-chains
    half2_t M0a = mk2(4.0f, 4.0f), M0b = M0a, M1a = M0a, M1b = M0a;

#pragma unroll
    for (int q = 0; q < 4; ++q) {       // b128 B group: ch 8q..8q+7 (pairs 4q..4q+3)
        bvec bq0[9], bq1[9];
#pragma unroll
        for (int t = 0; t < 9; ++t) {   // wave-uniform broadcast b128
            bq0[t].v8 = *(const half8_t*)&ldsB[f0][t][8 * q];
            bq1[t].v8 = *(const half8_t*)&ldsB[f0 + 1][t][8 * q];
        }
#pragma unroll
        for (int h = 0; h < 2; ++h) {   // A slot s = 2q+h: pairs 4q+2h, 4q+2h+1
            const int s = 2 * q + h;
            half4_t a[KS][KS];
#pragma unroll
            for (int kr = 0; kr < KS; ++kr)
#pragma unroll
                for (int kw = 0; kw < KS; ++kw)
                    a[kr][kw] = ldsA[s][kr][lane + kw];
#pragma unroll
            for (int t = 0; t < 9; ++t) {
                half4_t av = a[t / 3][t % 3];
                half2_t alo = { av.x, av.y };       // pair 4q+2h
                half2_t ahi = { av.z, av.w };       // pair 4q+2h+1
                half2_t s0l = alo + bq0[t].v2[2 * h];
                half2_t s0h = ahi + bq0[t].v2[2 * h + 1];
                half2_t s1l = alo + bq1[t].v2[2 * h];
                half2_t s1h = ahi + bq1[t].v2[2 * h + 1];
                if (h) { M0b = __builtin_elementwise_min(M0b, s0l);
                         M0b = __builtin_elementwise_min(M0b, s0h);
                         M1b = __builtin_elementwise_min(M1b, s1l);
                         M1b = __builtin_elementwise_min(M1b, s1h); }
                else   { M0a = __builtin_elementwise_min(M0a, s0l);
                         M0a = __builtin_elementwise_min(M0a, s0h);
                         M1a = __builtin_elementwise_min(M1a, s1l);
                         M1a = __builtin_elementwise_min(M1a, s1h); }
            }
        }
    }

    half2_t M0 = __builtin_elementwise_min(M0a, M0b);
    half2_t M1 = __builtin_elementwise_min(M1a, M1b);
    float m0 = fminf((float)M0.x, (float)M0.y);
    float m1 = fminf((float)M1.x, (float)M1.y);
    float r0 = 1.0f - exp2f(0.6666666667f * log2f(m0));
    float r1 = 1.0f - exp2f(0.6666666667f * log2f(m1));
    float* op = out + (((size_t)b * FOUT + fg) * SS + row) * SS + lane;
    op[0]       = fmaxf(r0, 0.0f);
    op[SS * SS] = fmaxf(r1, 0.0f);
}

extern "C" void kernel_launch(void* const* d_in, const int* in_sizes, int n_in,
                              void* d_out, int out_size, void* d_ws, size_t ws_size,
                              hipStream_t stream)
{
    const float* x = (const float*)d_in[0];   // [4,32,66,66] f32
    const float* w = (const float*)d_in[1];   // [288,32] f32
    float* out = (float*)d_out;               // [4,32,64,64] f32
    (void)d_ws; (void)ws_size;

    yager_one<<<NB * SS * 2, 512, 0, stream>>>(x, w, out);
}

// Round 12
// 18.169 us; speedup vs baseline: 4.3452x; 2.3579x over previous
//
#include <hip/hip_runtime.h>
#include <math.h>

// MaxYager2d: out[b,f,si,sj] = max(0, 1 - (min_{c,kh,kw} A[b,c,si+kh,sj+kw] + BW[c,kh,kw,f])^(2/3))
// A = (1-x)^1.5, BW = (1-w)^1.5. Max over J commutes with the monotone-
// decreasing Yager combine -> tropical min-plus 3x3 conv.
//
// r12: NO LDS. r9 was LDS-instruction-issue-bound (~24k cy/CU). Here:
//  - prep: A4[b][r][s][col] half4 (4 ch, f16) + Bp[(fp,q) slabs] half2 -> ws
//  - main: 4096 independent waves (256-thr blocks, no barrier). A-taps are
//    coalesced global b64 loads (VMEM pipe, 3 base addrs + imm offsets,
//    L1/L2-hot); B is wave-uniform scalar loads (SMEM path, own counter —
//    no vmcnt/lgkmcnt interference). pk_add+pk_min as r5/r9 (absmax 3.9e-3).

#define CIN  32
#define FOUT 32
#define KS   3
#define HW   66   // input spatial
#define SS   64   // output spatial
#define NB   4    // batch
#define NSL  8    // half4 channel slots

typedef _Float16 half2_t __attribute__((ext_vector_type(2)));
typedef _Float16 half4_t __attribute__((ext_vector_type(4)));   // 8 B

static __device__ __forceinline__ half2_t mk2(float a, float b) {
    half2_t r; r.x = (_Float16)a; r.y = (_Float16)b; return r;
}
static __device__ __forceinline__ _Float16 yg(float v) {
    float t = 1.0f - v;
    return (_Float16)(t * sqrtf(t));   // (1-v)^1.5
}

#define NA4 (NB * HW * NSL * HW)       // 139392 half4
#define NBP (16 * 4 * 2 * 9 * 4)       // 4608 half2  [fp][q][f2][t][c4]

__global__ __launch_bounds__(256) void yager_prep(
    const float* __restrict__ x, const float* __restrict__ w,
    half4_t* __restrict__ A4, half2_t* __restrict__ Bp)
{
    int i = blockIdx.x * 256 + threadIdx.x;
    if (i < NA4) {
        // [b][r][s][col]
        int col = i % HW;
        int s   = (i / HW) & (NSL - 1);
        int r   = (i / (HW * NSL)) % HW;
        int b   = i / (HW * NSL * HW);
        const float* xp = x + (((size_t)b * CIN + 4 * s) * HW + r) * HW + col;
        half4_t v;
        v.x = yg(xp[0]);
        v.y = yg(xp[(size_t)HW * HW]);
        v.z = yg(xp[(size_t)2 * HW * HW]);
        v.w = yg(xp[(size_t)3 * HW * HW]);
        A4[i] = v;
    }
    if (i < NBP) {
        // [fp][q][f2][t][c4] ; channels 8q+2*c4, 8q+2*c4+1 ; f = fp*2+f2
        int c4 = i & 3;
        int t  = (i >> 2) % 9;
        int f2 = (i / 36) & 1;
        int q  = (i / 72) & 3;
        int fp = i / 288;
        int f  = fp * 2 + f2;
        int c0 = 8 * q + 2 * c4;
        float w0 = w[(c0 * 9 + t) * FOUT + f];
        float w1 = w[((c0 + 1) * 9 + t) * FOUT + f];
        Bp[i] = mk2(1.0f, 1.0f);
        float t0 = 1.0f - w0, t1 = 1.0f - w1;
        Bp[i] = mk2(t0 * sqrtf(t0), t1 * sqrtf(t1));
    }
}

__global__ __launch_bounds__(256) void yager_main(
    const half4_t* __restrict__ A4, const half2_t* __restrict__ Bp,
    float* __restrict__ out)
{
    const int tid  = threadIdx.x;
    const int lane = tid & 63;
    const int wgl  = blockIdx.x * 4 + (tid >> 6);   // global wave id
    const int fp   = __builtin_amdgcn_readfirstlane(wgl & 15);
    const int rowb = __builtin_amdgcn_readfirstlane(wgl >> 4);
    const int row  = rowb & (SS - 1);
    const int b    = rowb >> 6;

    // 3 per-lane base pointers (kr = 0,1,2); all 72 taps via imm offsets.
    const half4_t* Ar0 = A4 + ((size_t)(b * HW + row) * NSL) * HW + lane;
    const half4_t* Ar1 = Ar0 + (size_t)NSL * HW;
    const half4_t* Ar2 = Ar1 + (size_t)NSL * HW;

    const half2_t* __restrict__ bb = Bp + fp * 288;   // wave-uniform -> s_load

    half2_t Ma0 = mk2(4.0f, 4.0f), Mb0 = Ma0, Ma1 = Ma0, Mb1 = Ma0;

#pragma unroll
    for (int q = 0; q < 4; ++q) {
        // B slab for this q: [f2][t][c4], 72 half2, wave-uniform
        half2_t bv[2][9][4];
#pragma unroll
        for (int f2 = 0; f2 < 2; ++f2)
#pragma unroll
            for (int t = 0; t < 9; ++t)
#pragma unroll
                for (int c4 = 0; c4 < 4; ++c4)
                    bv[f2][t][c4] = bb[((q * 2 + f2) * 9 + t) * 4 + c4];

#pragma unroll
        for (int h = 0; h < 2; ++h) {
            const int s = 2 * q + h;         // channels 4s..4s+3
            half4_t a[9];
#pragma unroll
            for (int kw = 0; kw < KS; ++kw) {
                a[0 + kw] = Ar0[s * HW + kw];
                a[3 + kw] = Ar1[s * HW + kw];
                a[6 + kw] = Ar2[s * HW + kw];
            }
#pragma unroll
            for (int t = 0; t < 9; ++t) {
                half2_t alo = { a[t].x, a[t].y };   // cp c4=2h
                half2_t ahi = { a[t].z, a[t].w };   // cp c4=2h+1
                Ma0 = __builtin_elementwise_min(Ma0, (half2_t)(alo + bv[0][t][2 * h]));
                Mb0 = __builtin_elementwise_min(Mb0, (half2_t)(ahi + bv[0][t][2 * h + 1]));
                Ma1 = __builtin_elementwise_min(Ma1, (half2_t)(alo + bv[1][t][2 * h]));
                Mb1 = __builtin_elementwise_min(Mb1, (half2_t)(ahi + bv[1][t][2 * h + 1]));
            }
        }
    }

    half2_t M0 = __builtin_elementwise_min(Ma0, Mb0);
    half2_t M1 = __builtin_elementwise_min(Ma1, Mb1);
    float m0 = fminf((float)M0.x, (float)M0.y);
    float m1 = fminf((float)M1.x, (float)M1.y);
    float r0 = 1.0f - exp2f(0.6666666667f * log2f(m0));
    float r1 = 1.0f - exp2f(0.6666666667f * log2f(m1));
    float* op = out + (((size_t)b * FOUT + fp * 2) * SS + row) * SS + lane;
    op[0]       = fmaxf(r0, 0.0f);
    op[SS * SS] = fmaxf(r1, 0.0f);
}

// Fallback (r1-proven) if workspace too small.
__global__ __launch_bounds__(256) void yager_fused(
    const float* __restrict__ x, const float* __restrict__ w,
    float* __restrict__ out)
{
    __shared__ float bws[CIN * KS * KS * FOUT];
    for (int i = threadIdx.y * 64 + threadIdx.x; i < CIN * KS * KS * FOUT; i += 256) {
        float t = 1.0f - w[i];
        bws[i] = t * sqrtf(t);
    }
    __syncthreads();

    const int col = threadIdx.x;
    const int fg  = threadIdx.y;
    const int row = blockIdx.x & (SS - 1);
    const int b   = blockIdx.x >> 6;

    const float* xb = x + ((size_t)(b * CIN) * HW + row) * HW + col;
    float m[8];
#pragma unroll
    for (int f = 0; f < 8; ++f) m[f] = 3.0f;

    for (int c = 0; c < CIN; ++c) {
        const float* xc = xb + (size_t)c * HW * HW;
        const float* bc = bws + c * (KS * KS) * FOUT + fg * 8;
#pragma unroll
        for (int kh = 0; kh < KS; ++kh)
#pragma unroll
            for (int kw = 0; kw < KS; ++kw) {
                float t = 1.0f - xc[kh * HW + kw];
                const float a = t * sqrtf(t);
                const float* br = bc + (kh * KS + kw) * FOUT;
#pragma unroll
                for (int f = 0; f < 8; ++f)
                    m[f] = fminf(m[f], a + br[f]);
            }
    }

    float* op = out + (((size_t)b * FOUT + fg * 8) * SS + row) * SS + col;
#pragma unroll
    for (int f = 0; f < 8; ++f) {
        float r = 1.0f - exp2f(0.6666666667f * log2f(m[f]));
        op[(size_t)f * SS * SS] = fmaxf(r, 0.0f);
    }
}

extern "C" void kernel_launch(void* const* d_in, const int* in_sizes, int n_in,
                              void* d_out, int out_size, void* d_ws, size_t ws_size,
                              hipStream_t stream)
{
    const float* x = (const float*)d_in[0];   // [4,32,66,66] f32
    const float* w = (const float*)d_in[1];   // [288,32] f32
    float* out = (float*)d_out;               // [4,32,64,64] f32

    const size_t needA = (size_t)NA4 * sizeof(half4_t);        // 1,115,136 B
    const size_t need  = needA + (size_t)NBP * sizeof(half2_t);

    if (ws_size >= need) {
        half4_t* A4 = (half4_t*)d_ws;
        half2_t* Bp = (half2_t*)((char*)d_ws + needA);
        yager_prep<<<(NA4 + 255) / 256, 256, 0, stream>>>(x, w, A4, Bp);
        yager_main<<<NB * SS * 16 / 4, 256, 0, stream>>>(A4, Bp, out);
    } else {
        dim3 blk(64, 4);
        dim3 grd(NB * SS);
        yager_fused<<<grd, blk, 0, stream>>>(x, w, out);
    }
}